// Round 1
// baseline (1674.176 us; speedup 1.0000x reference)
//
#include <hip/hip_runtime.h>
#include <hip/hip_bf16.h>
#include <stdint.h>

#define T_TOKENS 8192
#define D_DIM    1024
#define F_DIM    4096
#define NE       8
#define MAXTILES 136
#define PAIR_CAP 17408

typedef unsigned short u16;
typedef __attribute__((ext_vector_type(8))) __bf16 bf16x8;
typedef __attribute__((ext_vector_type(4))) float  f32x4;

// ---------- helpers ----------
__device__ __forceinline__ u16 f2bf(float f) {
    __hip_bfloat16 h = __float2bfloat16(f);
    return *reinterpret_cast<u16*>(&h);
}

__device__ __forceinline__ void gl_lds16(const void* g, void* l) {
    __builtin_amdgcn_global_load_lds(
        (const __attribute__((address_space(1))) uint32_t*)g,
        (__attribute__((address_space(3))) uint32_t*)l, 16, 0, 0);
}

// ---------- ctrl layout (int indices into ws base) ----------
// [0..7]   counts
// [8..15]  cursor
// [16..24] off (9)
// [32]     n_tiles
// [64..199]  tile_e
// [256..391] tile_m0

// ---------- kernel 1: router ----------
__global__ __launch_bounds__(256) void k_router(
    const float* __restrict__ x, const float* __restrict__ gate_w,
    float* __restrict__ logits_out, int* __restrict__ ti,
    float* __restrict__ tw, int* __restrict__ ctrl)
{
    __shared__ float gw[NE * D_DIM];
    int tid = threadIdx.x;
    for (int i = tid; i < NE * D_DIM; i += 256) gw[i] = gate_w[i];
    __syncthreads();

    int wave = tid >> 6, lane = tid & 63;
    int t = blockIdx.x * 4 + wave;

    const float* xr = x + (size_t)t * D_DIM;
    float xv[16];
#pragma unroll
    for (int i = 0; i < 16; i++) xv[i] = xr[i * 64 + lane];

    float acc[NE];
#pragma unroll
    for (int e = 0; e < NE; e++) {
        float s = 0.f;
#pragma unroll
        for (int i = 0; i < 16; i++) s += xv[i] * gw[e * D_DIM + i * 64 + lane];
        for (int off = 32; off; off >>= 1) s += __shfl_down(s, off, 64);
        acc[e] = s;
    }

    if (lane == 0) {
#pragma unroll
        for (int e = 0; e < NE; e++) logits_out[t * NE + e] = acc[e];
        // top-2, lowest-index-wins on ties (matches jax.lax.top_k)
        int i0 = 0; float v0 = acc[0];
        for (int e = 1; e < NE; e++) if (acc[e] > v0) { v0 = acc[e]; i0 = e; }
        int i1 = -1; float v1 = -3.0e38f;
        for (int e = 0; e < NE; e++) if (e != i0 && acc[e] > v1) { v1 = acc[e]; i1 = e; }
        float e1 = expf(v1 - v0);
        float s  = 1.f + e1;
        float w0 = 1.f / s, w1 = e1 / s;
        ti[t * 2 + 0] = i0; ti[t * 2 + 1] = i1;
        tw[t * 2 + 0] = w0; tw[t * 2 + 1] = w1;
        atomicAdd(&ctrl[i0], 1);
        atomicAdd(&ctrl[i1], 1);
    }
}

// ---------- kernel 2: plan (single thread) ----------
__global__ void k_plan(int* __restrict__ ctrl)
{
    if (threadIdx.x != 0 || blockIdx.x != 0) return;
    int* counts  = ctrl;
    int* off     = ctrl + 16;
    int* tile_e  = ctrl + 64;
    int* tile_m0 = ctrl + 256;
    int o = 0, nt = 0;
    for (int e = 0; e < NE; e++) {
        off[e] = o;
        int c = counts[e];
        int tcnt = (c + 127) >> 7;
        for (int j = 0; j < tcnt; j++) { tile_e[nt] = e; tile_m0[nt] = o + j * 128; nt++; }
        o += tcnt << 7;
    }
    off[NE] = o;
    ctrl[32] = nt;
}

// ---------- kernel 3: scatter tokens to expert segments ----------
__global__ __launch_bounds__(256) void k_scatter(
    const int* __restrict__ ti, const float* __restrict__ tw,
    int* __restrict__ ctrl, int* __restrict__ pair_token, float* __restrict__ pair_w)
{
    int t = blockIdx.x * 256 + threadIdx.x;
    if (t >= T_TOKENS) return;
    int* off    = ctrl + 16;
    int* cursor = ctrl + 8;
#pragma unroll
    for (int k = 0; k < 2; k++) {
        int e = ti[t * 2 + k];
        int slot = off[e] + atomicAdd(&cursor[e], 1);
        pair_token[slot] = t;
        pair_w[slot] = tw[t * 2 + k];
    }
}

// ---------- kernel 4: x -> bf16 ----------
__global__ __launch_bounds__(256) void k_cvt_x(
    const float* __restrict__ x, u16* __restrict__ xb)
{
    size_t i = ((size_t)blockIdx.x * 256 + threadIdx.x) * 4;
    float4 v = *(const float4*)(x + i);
    ushort4 o;
    o.x = f2bf(v.x); o.y = f2bf(v.y); o.z = f2bf(v.z); o.w = f2bf(v.w);
    *(ushort4*)(xb + i) = o;
}

// ---------- kernel 5: transpose + convert weights ----------
// src [R][C] f32  ->  dst [C][R] bf16   (per blockIdx.z expert)
__global__ __launch_bounds__(256) void k_transpose_cvt(
    const float* __restrict__ src, u16* __restrict__ dst, int R, int C)
{
    __shared__ float tile[32][33];
    size_t base = (size_t)blockIdx.z * R * C;
    src += base; dst += base;
    int c0 = blockIdx.x * 32, r0 = blockIdx.y * 32;
    int tx = threadIdx.x & 31, ty = threadIdx.x >> 5;  // 32 x 8
#pragma unroll
    for (int i = 0; i < 32; i += 8)
        tile[ty + i][tx] = src[(size_t)(r0 + ty + i) * C + c0 + tx];
    __syncthreads();
#pragma unroll
    for (int i = 0; i < 32; i += 8)
        dst[(size_t)(c0 + ty + i) * R + r0 + tx] = f2bf(tile[tx][ty + i]);
}

// ---------- kernel 6: GEMM1  h = silu(Xe @ W1) * (Xe @ W3) ----------
// A rows gathered via pair_token; B from [N][K]-layout bf16 weights.
__global__ __launch_bounds__(256) void k_gemm1(
    const u16* __restrict__ xb, const u16* __restrict__ w1t,
    const u16* __restrict__ w3t, u16* __restrict__ h,
    const int* __restrict__ pair_token, const int* __restrict__ ctrl)
{
    int ntiles = ctrl[32];
    int tile = blockIdx.x;
    if (tile >= ntiles) return;
    int e  = ctrl[64 + tile];
    int m0 = ctrl[256 + tile];
    int n0 = blockIdx.y * 128;

    const u16* w1e = w1t + (size_t)e * F_DIM * D_DIM;
    const u16* w3e = w3t + (size_t)e * F_DIM * D_DIM;

    __shared__ __align__(16) u16 As[128 * 32];
    __shared__ __align__(16) u16 B1s[128 * 32];
    __shared__ __align__(16) u16 B3s[128 * 32];

    int tid  = threadIdx.x;
    int lane = tid & 63, wave = tid >> 6;

    // staging: chunk id = row*4 + kc (16B chunks); thread covers chunk tid and tid+256
    int r_a = tid >> 2, kc = tid & 3;
    int tok0 = pair_token[m0 + r_a];
    int tok1 = pair_token[m0 + r_a + 64];
    const u16* gA0 = xb  + (size_t)tok0 * D_DIM + kc * 8;
    const u16* gA1 = xb  + (size_t)tok1 * D_DIM + kc * 8;
    const u16* gB10 = w1e + (size_t)(n0 + r_a) * D_DIM + kc * 8;
    const u16* gB11 = w1e + (size_t)(n0 + r_a + 64) * D_DIM + kc * 8;
    const u16* gB30 = w3e + (size_t)(n0 + r_a) * D_DIM + kc * 8;
    const u16* gB31 = w3e + (size_t)(n0 + r_a + 64) * D_DIM + kc * 8;
    u16* lA0  = As  + tid * 8;
    u16* lA1  = As  + tid * 8 + 2048;
    u16* lB10 = B1s + tid * 8;
    u16* lB11 = B1s + tid * 8 + 2048;
    u16* lB30 = B3s + tid * 8;
    u16* lB31 = B3s + tid * 8 + 2048;

    int wr = wave >> 1, wc = wave & 1;
    int quad = lane >> 4, mn = lane & 15;

    f32x4 acc1[4][4] = {};
    f32x4 acc3[4][4] = {};

    for (int k0 = 0; k0 < D_DIM; k0 += 32) {
        gl_lds16(gA0 + k0, lA0);   gl_lds16(gA1 + k0, lA1);
        gl_lds16(gB10 + k0, lB10); gl_lds16(gB11 + k0, lB11);
        gl_lds16(gB30 + k0, lB30); gl_lds16(gB31 + k0, lB31);
        __syncthreads();

        bf16x8 af[4], b1f[4], b3f[4];
#pragma unroll
        for (int i = 0; i < 4; i++)
            af[i] = *(const bf16x8*)(As + (wr * 64 + i * 16 + mn) * 32 + quad * 8);
#pragma unroll
        for (int j = 0; j < 4; j++) {
            b1f[j] = *(const bf16x8*)(B1s + (wc * 64 + j * 16 + mn) * 32 + quad * 8);
            b3f[j] = *(const bf16x8*)(B3s + (wc * 64 + j * 16 + mn) * 32 + quad * 8);
        }
#pragma unroll
        for (int i = 0; i < 4; i++)
#pragma unroll
            for (int j = 0; j < 4; j++) {
                acc1[i][j] = __builtin_amdgcn_mfma_f32_16x16x32_bf16(af[i], b1f[j], acc1[i][j], 0, 0, 0);
                acc3[i][j] = __builtin_amdgcn_mfma_f32_16x16x32_bf16(af[i], b3f[j], acc3[i][j], 0, 0, 0);
            }
        __syncthreads();
    }

#pragma unroll
    for (int i = 0; i < 4; i++)
#pragma unroll
        for (int j = 0; j < 4; j++)
#pragma unroll
            for (int r = 0; r < 4; r++) {
                int row = wr * 64 + i * 16 + quad * 4 + r;
                int col = n0 + wc * 64 + j * 16 + mn;
                float v1 = acc1[i][j][r];
                float v3 = acc3[i][j][r];
                float hv = v1 * (1.f / (1.f + __expf(-v1))) * v3;  // silu(v1)*v3
                h[(size_t)(m0 + row) * F_DIM + col] = f2bf(hv);
            }
}

// ---------- kernel 7: GEMM2  out += (h @ W2) * w ----------
__global__ __launch_bounds__(256) void k_gemm2(
    const u16* __restrict__ h, const u16* __restrict__ w2t,
    float* __restrict__ out, const int* __restrict__ pair_token,
    const float* __restrict__ pair_w, const int* __restrict__ ctrl)
{
    int ntiles = ctrl[32];
    int tile = blockIdx.x;
    if (tile >= ntiles) return;
    int e  = ctrl[64 + tile];
    int m0 = ctrl[256 + tile];
    int n0 = blockIdx.y * 128;

    const u16* w2e = w2t + (size_t)e * D_DIM * F_DIM;

    __shared__ __align__(16) u16 As[128 * 32];
    __shared__ __align__(16) u16 Bs[128 * 32];

    int tid  = threadIdx.x;
    int lane = tid & 63, wave = tid >> 6;

    int r_a = tid >> 2, kc = tid & 3;
    const u16* gA0 = h   + (size_t)(m0 + r_a) * F_DIM + kc * 8;
    const u16* gA1 = h   + (size_t)(m0 + r_a + 64) * F_DIM + kc * 8;
    const u16* gB0 = w2e + (size_t)(n0 + r_a) * F_DIM + kc * 8;
    const u16* gB1 = w2e + (size_t)(n0 + r_a + 64) * F_DIM + kc * 8;
    u16* lA0 = As + tid * 8;
    u16* lA1 = As + tid * 8 + 2048;
    u16* lB0 = Bs + tid * 8;
    u16* lB1 = Bs + tid * 8 + 2048;

    int wr = wave >> 1, wc = wave & 1;
    int quad = lane >> 4, mn = lane & 15;

    f32x4 acc[4][4] = {};

    for (int k0 = 0; k0 < F_DIM; k0 += 32) {
        gl_lds16(gA0 + k0, lA0);
        gl_lds16(gA1 + k0, lA1);
        gl_lds16(gB0 + k0, lB0);
        gl_lds16(gB1 + k0, lB1);
        __syncthreads();

        bf16x8 af[4], bf[4];
#pragma unroll
        for (int i = 0; i < 4; i++)
            af[i] = *(const bf16x8*)(As + (wr * 64 + i * 16 + mn) * 32 + quad * 8);
#pragma unroll
        for (int j = 0; j < 4; j++)
            bf[j] = *(const bf16x8*)(Bs + (wc * 64 + j * 16 + mn) * 32 + quad * 8);
#pragma unroll
        for (int i = 0; i < 4; i++)
#pragma unroll
            for (int j = 0; j < 4; j++)
                acc[i][j] = __builtin_amdgcn_mfma_f32_16x16x32_bf16(af[i], bf[j], acc[i][j], 0, 0, 0);
        __syncthreads();
    }

#pragma unroll
    for (int i = 0; i < 4; i++)
#pragma unroll
        for (int r = 0; r < 4; r++) {
            int row = wr * 64 + i * 16 + quad * 4 + r;
            int prow = m0 + row;
            int tokv = pair_token[prow];
            float wv = pair_w[prow];
#pragma unroll
            for (int j = 0; j < 4; j++) {
                int col = n0 + wc * 64 + j * 16 + mn;
                atomicAdd(&out[(size_t)tokv * D_DIM + col], acc[i][j][r] * wv);
            }
        }
}

// ---------- launch ----------
extern "C" void kernel_launch(void* const* d_in, const int* in_sizes, int n_in,
                              void* d_out, int out_size, void* d_ws, size_t ws_size,
                              hipStream_t stream)
{
    const float* x      = (const float*)d_in[0];
    const float* gate_w = (const float*)d_in[1];
    const float* W1     = (const float*)d_in[2];
    const float* W3     = (const float*)d_in[3];
    const float* W2     = (const float*)d_in[4];
    float* out = (float*)d_out;
    float* logits_out = out + (size_t)T_TOKENS * D_DIM;

    char* ws = (char*)d_ws;
    int*   ctrl       = (int*)ws;                    // 4096 B (incl tile map)
    int*   pair_token = (int*)(ws + 4096);           // 69632 B
    float* pair_w     = (float*)(ws + 4096 + 69632); // 69632 B
    int*   ti         = (int*)(ws + 143360);         // 65536 B
    float* tw         = (float*)(ws + 208896);       // 65536 B
    u16*   xb         = (u16*)(ws + 1048576);        // 16 MiB
    u16*   w1t        = (u16*)(ws + 17825792);       // 64 MiB
    u16*   w3t        = (u16*)(ws + 84934656);       // 64 MiB
    u16*   w2t        = (u16*)(ws + 152043520);      // 64 MiB
    u16*   h          = (u16*)(ws + 219152384);      // 136 MiB (17408 x 4096 bf16)

    hipMemsetAsync(d_out, 0, (size_t)T_TOKENS * D_DIM * sizeof(float), stream);
    hipMemsetAsync(ws, 0, 143360, stream);  // ctrl + pair arrays

    k_router<<<T_TOKENS / 4, 256, 0, stream>>>(x, gate_w, logits_out, ti, tw, ctrl);
    k_plan<<<1, 64, 0, stream>>>(ctrl);
    k_scatter<<<T_TOKENS / 256, 256, 0, stream>>>(ti, tw, ctrl, pair_token, pair_w);

    k_cvt_x<<<(T_TOKENS * D_DIM) / (256 * 4), 256, 0, stream>>>(x, xb);
    dim3 tg1(128, 32, NE);  // W1/W3: R=1024, C=4096
    k_transpose_cvt<<<tg1, 256, 0, stream>>>(W1, w1t, D_DIM, F_DIM);
    k_transpose_cvt<<<tg1, 256, 0, stream>>>(W3, w3t, D_DIM, F_DIM);
    dim3 tg2(32, 128, NE);  // W2: R=4096, C=1024
    k_transpose_cvt<<<tg2, 256, 0, stream>>>(W2, w2t, F_DIM, D_DIM);

    dim3 g1(MAXTILES, F_DIM / 128);
    k_gemm1<<<g1, 256, 0, stream>>>(xb, w1t, w3t, h, pair_token, ctrl);
    dim3 g2(MAXTILES, D_DIM / 128);
    k_gemm2<<<g2, 256, 0, stream>>>(h, w2t, out, pair_token, pair_w, ctrl);
}

// Round 2
// 1511.183 us; speedup vs baseline: 1.1079x; 1.1079x over previous
//
#include <hip/hip_runtime.h>
#include <hip/hip_bf16.h>
#include <stdint.h>

#define T_TOKENS 8192
#define D_DIM    1024
#define F_DIM    4096
#define NE       8
#define MAXTILES 136
#define PAIR_CAP 17408

typedef unsigned short u16;
typedef __attribute__((ext_vector_type(8))) __bf16 bf16x8;
typedef __attribute__((ext_vector_type(4))) float  f32x4;

// ---------- helpers ----------
__device__ __forceinline__ u16 f2bf(float f) {
    __hip_bfloat16 h = __float2bfloat16(f);
    return *reinterpret_cast<u16*>(&h);
}

__device__ __forceinline__ float bf2f(u16 r) {
    uint32_t u = ((uint32_t)r) << 16;
    return __uint_as_float(u);
}

__device__ __forceinline__ void gl_lds16(const void* g, void* l) {
    __builtin_amdgcn_global_load_lds(
        (const __attribute__((address_space(1))) uint32_t*)g,
        (__attribute__((address_space(3))) uint32_t*)l, 16, 0, 0);
}

// ---------- ctrl layout (int indices into ws base) ----------
// [0..7]   counts
// [8..15]  cursor
// [16..24] off (9)
// [32]     n_tiles
// [64..199]  tile_e
// [256..391] tile_m0

// ---------- kernel 1: router ----------
__global__ __launch_bounds__(256) void k_router(
    const float* __restrict__ x, const float* __restrict__ gate_w,
    float* __restrict__ logits_out, int* __restrict__ ti,
    float* __restrict__ tw, int* __restrict__ ctrl)
{
    __shared__ float gw[NE * D_DIM];
    int tid = threadIdx.x;
    for (int i = tid; i < NE * D_DIM; i += 256) gw[i] = gate_w[i];
    __syncthreads();

    int wave = tid >> 6, lane = tid & 63;
    int t = blockIdx.x * 4 + wave;

    const float* xr = x + (size_t)t * D_DIM;
    float xv[16];
#pragma unroll
    for (int i = 0; i < 16; i++) xv[i] = xr[i * 64 + lane];

    float acc[NE];
#pragma unroll
    for (int e = 0; e < NE; e++) {
        float s = 0.f;
#pragma unroll
        for (int i = 0; i < 16; i++) s += xv[i] * gw[e * D_DIM + i * 64 + lane];
        for (int off = 32; off; off >>= 1) s += __shfl_down(s, off, 64);
        acc[e] = s;
    }

    if (lane == 0) {
#pragma unroll
        for (int e = 0; e < NE; e++) logits_out[t * NE + e] = acc[e];
        // top-2, lowest-index-wins on ties (matches jax.lax.top_k)
        int i0 = 0; float v0 = acc[0];
        for (int e = 1; e < NE; e++) if (acc[e] > v0) { v0 = acc[e]; i0 = e; }
        int i1 = -1; float v1 = -3.0e38f;
        for (int e = 0; e < NE; e++) if (e != i0 && acc[e] > v1) { v1 = acc[e]; i1 = e; }
        float e1 = expf(v1 - v0);
        float s  = 1.f + e1;
        float w0 = 1.f / s, w1 = e1 / s;
        ti[t * 2 + 0] = i0; ti[t * 2 + 1] = i1;
        tw[t * 2 + 0] = w0; tw[t * 2 + 1] = w1;
        atomicAdd(&ctrl[i0], 1);
        atomicAdd(&ctrl[i1], 1);
    }
}

// ---------- kernel 2: plan (single thread) ----------
__global__ void k_plan(int* __restrict__ ctrl)
{
    if (threadIdx.x != 0 || blockIdx.x != 0) return;
    int* counts  = ctrl;
    int* off     = ctrl + 16;
    int* tile_e  = ctrl + 64;
    int* tile_m0 = ctrl + 256;
    int o = 0, nt = 0;
    for (int e = 0; e < NE; e++) {
        off[e] = o;
        int c = counts[e];
        int tcnt = (c + 127) >> 7;
        for (int j = 0; j < tcnt; j++) { tile_e[nt] = e; tile_m0[nt] = o + j * 128; nt++; }
        o += tcnt << 7;
    }
    off[NE] = o;
    ctrl[32] = nt;
}

// ---------- kernel 3: scatter tokens to expert segments ----------
__global__ __launch_bounds__(256) void k_scatter(
    const int* __restrict__ ti, const float* __restrict__ tw,
    int* __restrict__ ctrl, int* __restrict__ pair_token, float* __restrict__ pair_w)
{
    int t = blockIdx.x * 256 + threadIdx.x;
    if (t >= T_TOKENS) return;
    int* off    = ctrl + 16;
    int* cursor = ctrl + 8;
#pragma unroll
    for (int k = 0; k < 2; k++) {
        int e = ti[t * 2 + k];
        int slot = off[e] + atomicAdd(&cursor[e], 1);
        pair_token[slot] = t;
        pair_w[slot] = tw[t * 2 + k];
    }
}

// ---------- kernel 4: x -> bf16 ----------
__global__ __launch_bounds__(256) void k_cvt_x(
    const float* __restrict__ x, u16* __restrict__ xb)
{
    size_t i = ((size_t)blockIdx.x * 256 + threadIdx.x) * 4;
    float4 v = *(const float4*)(x + i);
    ushort4 o;
    o.x = f2bf(v.x); o.y = f2bf(v.y); o.z = f2bf(v.z); o.w = f2bf(v.w);
    *(ushort4*)(xb + i) = o;
}

// ---------- kernel 5: transpose + convert weights ----------
// src [R][C] f32  ->  dst [C][R] bf16   (per blockIdx.z expert)
__global__ __launch_bounds__(256) void k_transpose_cvt(
    const float* __restrict__ src, u16* __restrict__ dst, int R, int C)
{
    __shared__ float tile[32][33];
    size_t base = (size_t)blockIdx.z * R * C;
    src += base; dst += base;
    int c0 = blockIdx.x * 32, r0 = blockIdx.y * 32;
    int tx = threadIdx.x & 31, ty = threadIdx.x >> 5;  // 32 x 8
#pragma unroll
    for (int i = 0; i < 32; i += 8)
        tile[ty + i][tx] = src[(size_t)(r0 + ty + i) * C + c0 + tx];
    __syncthreads();
#pragma unroll
    for (int i = 0; i < 32; i += 8)
        dst[(size_t)(c0 + ty + i) * R + r0 + tx] = f2bf(tile[tx][ty + i]);
}

// ---------- kernel 6: GEMM1 pass (m97-shape, single 4x4 accumulator) ----------
// MODE 0: v = Xe @ W1^T, hbuf = silu(v)          (bf16)
// MODE 1: v = Xe @ W3^T, hbuf = hbuf * v (in place; same thread reads+writes)
template<int MODE>
__global__ __launch_bounds__(256) void k_gemm1x(
    const u16* __restrict__ xb, const u16* __restrict__ wt,
    u16* __restrict__ hbuf, const int* __restrict__ pair_token,
    const int* __restrict__ ctrl)
{
    int ntiles = ctrl[32];
    int tile = blockIdx.x;
    if (tile >= ntiles) return;
    int e  = ctrl[64 + tile];
    int m0 = ctrl[256 + tile];
    int n0 = blockIdx.y * 128;

    const u16* we = wt + (size_t)e * F_DIM * D_DIM;

    __shared__ __align__(16) u16 As[128 * 32];
    __shared__ __align__(16) u16 Bs[128 * 32];

    int tid  = threadIdx.x;
    int lane = tid & 63, wave = tid >> 6;

    // staging: 16B chunks; thread covers row r_a and r_a+64 of each 128x32 tile
    int r_a = tid >> 2, kc = tid & 3;
    int tok0 = pair_token[m0 + r_a];
    int tok1 = pair_token[m0 + r_a + 64];
    const u16* gA0 = xb + (size_t)tok0 * D_DIM + kc * 8;
    const u16* gA1 = xb + (size_t)tok1 * D_DIM + kc * 8;
    const u16* gB0 = we + (size_t)(n0 + r_a) * D_DIM + kc * 8;
    const u16* gB1 = we + (size_t)(n0 + r_a + 64) * D_DIM + kc * 8;
    u16* lA0 = As + tid * 8;
    u16* lA1 = As + tid * 8 + 2048;
    u16* lB0 = Bs + tid * 8;
    u16* lB1 = Bs + tid * 8 + 2048;

    int wr = wave >> 1, wc = wave & 1;
    int quad = lane >> 4, mn = lane & 15;

    f32x4 acc[4][4] = {};

    for (int k0 = 0; k0 < D_DIM; k0 += 32) {
        gl_lds16(gA0 + k0, lA0);
        gl_lds16(gA1 + k0, lA1);
        gl_lds16(gB0 + k0, lB0);
        gl_lds16(gB1 + k0, lB1);
        __syncthreads();

        bf16x8 af[4], bf[4];
#pragma unroll
        for (int i = 0; i < 4; i++)
            af[i] = *(const bf16x8*)(As + (wr * 64 + i * 16 + mn) * 32 + quad * 8);
#pragma unroll
        for (int j = 0; j < 4; j++)
            bf[j] = *(const bf16x8*)(Bs + (wc * 64 + j * 16 + mn) * 32 + quad * 8);
#pragma unroll
        for (int i = 0; i < 4; i++)
#pragma unroll
            for (int j = 0; j < 4; j++)
                acc[i][j] = __builtin_amdgcn_mfma_f32_16x16x32_bf16(af[i], bf[j], acc[i][j], 0, 0, 0);
        __syncthreads();
    }

#pragma unroll
    for (int i = 0; i < 4; i++)
#pragma unroll
        for (int j = 0; j < 4; j++)
#pragma unroll
            for (int r = 0; r < 4; r++) {
                int row = wr * 64 + i * 16 + quad * 4 + r;
                int col = n0 + wc * 64 + j * 16 + mn;
                size_t idx = (size_t)(m0 + row) * F_DIM + col;
                float v = acc[i][j][r];
                if (MODE == 0) {
                    float s = v * (1.f / (1.f + __expf(-v)));   // silu(v1)
                    hbuf[idx] = f2bf(s);
                } else {
                    float s = bf2f(hbuf[idx]);                  // silu(v1)
                    hbuf[idx] = f2bf(s * v);                    // * v3
                }
            }
}

// ---------- kernel 7: GEMM2  out += (h @ W2^T) * w ----------
__global__ __launch_bounds__(256) void k_gemm2(
    const u16* __restrict__ h, const u16* __restrict__ w2t,
    float* __restrict__ out, const int* __restrict__ pair_token,
    const float* __restrict__ pair_w, const int* __restrict__ ctrl)
{
    int ntiles = ctrl[32];
    int tile = blockIdx.x;
    if (tile >= ntiles) return;
    int e  = ctrl[64 + tile];
    int m0 = ctrl[256 + tile];
    int n0 = blockIdx.y * 128;

    const u16* w2e = w2t + (size_t)e * D_DIM * F_DIM;

    __shared__ __align__(16) u16 As[128 * 32];
    __shared__ __align__(16) u16 Bs[128 * 32];

    int tid  = threadIdx.x;
    int lane = tid & 63, wave = tid >> 6;

    int r_a = tid >> 2, kc = tid & 3;
    const u16* gA0 = h   + (size_t)(m0 + r_a) * F_DIM + kc * 8;
    const u16* gA1 = h   + (size_t)(m0 + r_a + 64) * F_DIM + kc * 8;
    const u16* gB0 = w2e + (size_t)(n0 + r_a) * F_DIM + kc * 8;
    const u16* gB1 = w2e + (size_t)(n0 + r_a + 64) * F_DIM + kc * 8;
    u16* lA0 = As + tid * 8;
    u16* lA1 = As + tid * 8 + 2048;
    u16* lB0 = Bs + tid * 8;
    u16* lB1 = Bs + tid * 8 + 2048;

    int wr = wave >> 1, wc = wave & 1;
    int quad = lane >> 4, mn = lane & 15;

    f32x4 acc[4][4] = {};

    for (int k0 = 0; k0 < F_DIM; k0 += 32) {
        gl_lds16(gA0 + k0, lA0);
        gl_lds16(gA1 + k0, lA1);
        gl_lds16(gB0 + k0, lB0);
        gl_lds16(gB1 + k0, lB1);
        __syncthreads();

        bf16x8 af[4], bf[4];
#pragma unroll
        for (int i = 0; i < 4; i++)
            af[i] = *(const bf16x8*)(As + (wr * 64 + i * 16 + mn) * 32 + quad * 8);
#pragma unroll
        for (int j = 0; j < 4; j++)
            bf[j] = *(const bf16x8*)(Bs + (wc * 64 + j * 16 + mn) * 32 + quad * 8);
#pragma unroll
        for (int i = 0; i < 4; i++)
#pragma unroll
            for (int j = 0; j < 4; j++)
                acc[i][j] = __builtin_amdgcn_mfma_f32_16x16x32_bf16(af[i], bf[j], acc[i][j], 0, 0, 0);
        __syncthreads();
    }

#pragma unroll
    for (int i = 0; i < 4; i++)
#pragma unroll
        for (int r = 0; r < 4; r++) {
            int row = wr * 64 + i * 16 + quad * 4 + r;
            int prow = m0 + row;
            int tokv = pair_token[prow];
            float wv = pair_w[prow];
#pragma unroll
            for (int j = 0; j < 4; j++) {
                int col = n0 + wc * 64 + j * 16 + mn;
                atomicAdd(&out[(size_t)tokv * D_DIM + col], acc[i][j][r] * wv);
            }
        }
}

// ---------- launch ----------
extern "C" void kernel_launch(void* const* d_in, const int* in_sizes, int n_in,
                              void* d_out, int out_size, void* d_ws, size_t ws_size,
                              hipStream_t stream)
{
    const float* x      = (const float*)d_in[0];
    const float* gate_w = (const float*)d_in[1];
    const float* W1     = (const float*)d_in[2];
    const float* W3     = (const float*)d_in[3];
    const float* W2     = (const float*)d_in[4];
    float* out = (float*)d_out;
    float* logits_out = out + (size_t)T_TOKENS * D_DIM;

    char* ws = (char*)d_ws;
    int*   ctrl       = (int*)ws;                    // 4096 B (incl tile map)
    int*   pair_token = (int*)(ws + 4096);           // 69632 B
    float* pair_w     = (float*)(ws + 4096 + 69632); // 69632 B
    int*   ti         = (int*)(ws + 143360);         // 65536 B
    float* tw         = (float*)(ws + 208896);       // 65536 B
    u16*   xb         = (u16*)(ws + 1048576);        // 16 MiB
    u16*   w1t        = (u16*)(ws + 17825792);       // 64 MiB
    u16*   w3t        = (u16*)(ws + 84934656);       // 64 MiB
    u16*   w2t        = (u16*)(ws + 152043520);      // 64 MiB
    u16*   h          = (u16*)(ws + 219152384);      // 136 MiB (17408 x 4096 bf16)

    hipMemsetAsync(d_out, 0, (size_t)T_TOKENS * D_DIM * sizeof(float), stream);
    hipMemsetAsync(ws, 0, 143360, stream);  // ctrl + pair arrays

    k_router<<<T_TOKENS / 4, 256, 0, stream>>>(x, gate_w, logits_out, ti, tw, ctrl);
    k_plan<<<1, 64, 0, stream>>>(ctrl);
    k_scatter<<<T_TOKENS / 256, 256, 0, stream>>>(ti, tw, ctrl, pair_token, pair_w);

    k_cvt_x<<<(T_TOKENS * D_DIM) / (256 * 4), 256, 0, stream>>>(x, xb);
    dim3 tg1(128, 32, NE);  // W1/W3: R=1024, C=4096
    k_transpose_cvt<<<tg1, 256, 0, stream>>>(W1, w1t, D_DIM, F_DIM);
    k_transpose_cvt<<<tg1, 256, 0, stream>>>(W3, w3t, D_DIM, F_DIM);
    dim3 tg2(32, 128, NE);  // W2: R=4096, C=1024
    k_transpose_cvt<<<tg2, 256, 0, stream>>>(W2, w2t, F_DIM, D_DIM);

    dim3 g1(MAXTILES, F_DIM / 128);
    k_gemm1x<0><<<g1, 256, 0, stream>>>(xb, w1t, h, pair_token, ctrl);
    k_gemm1x<1><<<g1, 256, 0, stream>>>(xb, w3t, h, pair_token, ctrl);
    dim3 g2(MAXTILES, D_DIM / 128);
    k_gemm2<<<g2, 256, 0, stream>>>(h, w2t, out, pair_token, pair_w, ctrl);
}

// Round 3
// 1373.797 us; speedup vs baseline: 1.2186x; 1.1000x over previous
//
#include <hip/hip_runtime.h>
#include <hip/hip_bf16.h>
#include <stdint.h>

#define T_TOKENS 8192
#define D_DIM    1024
#define F_DIM    4096
#define NE       8
#define MAXTILES 136
#define PAIR_CAP 17408

typedef unsigned short u16;
typedef __attribute__((ext_vector_type(8))) __bf16 bf16x8;
typedef __attribute__((ext_vector_type(4))) float  f32x4;

// ---------- helpers ----------
__device__ __forceinline__ u16 f2bf(float f) {
    __hip_bfloat16 h = __float2bfloat16(f);
    return *reinterpret_cast<u16*>(&h);
}

__device__ __forceinline__ float bf2f(u16 r) {
    uint32_t u = ((uint32_t)r) << 16;
    return __uint_as_float(u);
}

__device__ __forceinline__ void gl_lds16(const void* g, void* l) {
    __builtin_amdgcn_global_load_lds(
        (const __attribute__((address_space(1))) uint32_t*)g,
        (__attribute__((address_space(3))) uint32_t*)l, 16, 0, 0);
}

// ---------- ctrl layout (int indices into ws base) ----------
// [0..7] counts  [8..15] cursor  [16..24] off  [32] n_tiles
// [64..199] tile_e  [256..391] tile_m0

// ---------- kernel 1: router ----------
__global__ __launch_bounds__(256) void k_router(
    const float* __restrict__ x, const float* __restrict__ gate_w,
    float* __restrict__ logits_out, int* __restrict__ ti,
    float* __restrict__ tw, int* __restrict__ ctrl)
{
    __shared__ float gw[NE * D_DIM];
    int tid = threadIdx.x;
    for (int i = tid; i < NE * D_DIM; i += 256) gw[i] = gate_w[i];
    __syncthreads();

    int wave = tid >> 6, lane = tid & 63;
    int t = blockIdx.x * 4 + wave;

    const float* xr = x + (size_t)t * D_DIM;
    float xv[16];
#pragma unroll
    for (int i = 0; i < 16; i++) xv[i] = xr[i * 64 + lane];

    float acc[NE];
#pragma unroll
    for (int e = 0; e < NE; e++) {
        float s = 0.f;
#pragma unroll
        for (int i = 0; i < 16; i++) s += xv[i] * gw[e * D_DIM + i * 64 + lane];
        for (int off = 32; off; off >>= 1) s += __shfl_down(s, off, 64);
        acc[e] = s;
    }

    if (lane == 0) {
#pragma unroll
        for (int e = 0; e < NE; e++) logits_out[t * NE + e] = acc[e];
        int i0 = 0; float v0 = acc[0];
        for (int e = 1; e < NE; e++) if (acc[e] > v0) { v0 = acc[e]; i0 = e; }
        int i1 = -1; float v1 = -3.0e38f;
        for (int e = 0; e < NE; e++) if (e != i0 && acc[e] > v1) { v1 = acc[e]; i1 = e; }
        float e1 = expf(v1 - v0);
        float s  = 1.f + e1;
        float w0 = 1.f / s, w1 = e1 / s;
        ti[t * 2 + 0] = i0; ti[t * 2 + 1] = i1;
        tw[t * 2 + 0] = w0; tw[t * 2 + 1] = w1;
        atomicAdd(&ctrl[i0], 1);
        atomicAdd(&ctrl[i1], 1);
    }
}

// ---------- kernel 2: plan ----------
__global__ void k_plan(int* __restrict__ ctrl)
{
    if (threadIdx.x != 0 || blockIdx.x != 0) return;
    int* counts  = ctrl;
    int* off     = ctrl + 16;
    int* tile_e  = ctrl + 64;
    int* tile_m0 = ctrl + 256;
    int o = 0, nt = 0;
    for (int e = 0; e < NE; e++) {
        off[e] = o;
        int c = counts[e];
        int tcnt = (c + 127) >> 7;
        for (int j = 0; j < tcnt; j++) { tile_e[nt] = e; tile_m0[nt] = o + j * 128; nt++; }
        o += tcnt << 7;
    }
    off[NE] = o;
    ctrl[32] = nt;
}

// ---------- kernel 3: scatter ----------
__global__ __launch_bounds__(256) void k_scatter(
    const int* __restrict__ ti, const float* __restrict__ tw,
    int* __restrict__ ctrl, int* __restrict__ pair_token, float* __restrict__ pair_w)
{
    int t = blockIdx.x * 256 + threadIdx.x;
    if (t >= T_TOKENS) return;
    int* off    = ctrl + 16;
    int* cursor = ctrl + 8;
#pragma unroll
    for (int k = 0; k < 2; k++) {
        int e = ti[t * 2 + k];
        int slot = off[e] + atomicAdd(&cursor[e], 1);
        pair_token[slot] = t;
        pair_w[slot] = tw[t * 2 + k];
    }
}

// ---------- kernel 4: x -> bf16 ----------
__global__ __launch_bounds__(256) void k_cvt_x(
    const float* __restrict__ x, u16* __restrict__ xb)
{
    size_t i = ((size_t)blockIdx.x * 256 + threadIdx.x) * 4;
    float4 v = *(const float4*)(x + i);
    ushort4 o;
    o.x = f2bf(v.x); o.y = f2bf(v.y); o.z = f2bf(v.z); o.w = f2bf(v.w);
    *(ushort4*)(xb + i) = o;
}

// ---------- kernel 5: transpose + convert weights ----------
__global__ __launch_bounds__(256) void k_transpose_cvt(
    const float* __restrict__ src, u16* __restrict__ dst, int R, int C)
{
    __shared__ float tile[32][33];
    size_t base = (size_t)blockIdx.z * R * C;
    src += base; dst += base;
    int c0 = blockIdx.x * 32, r0 = blockIdx.y * 32;
    int tx = threadIdx.x & 31, ty = threadIdx.x >> 5;  // 32 x 8
#pragma unroll
    for (int i = 0; i < 32; i += 8)
        tile[ty + i][tx] = src[(size_t)(r0 + ty + i) * C + c0 + tx];
    __syncthreads();
#pragma unroll
    for (int i = 0; i < 32; i += 8)
        dst[(size_t)(c0 + ty + i) * R + r0 + tx] = f2bf(tile[tx][ty + i]);
}

// ---------- kernel 6: GEMM1 pass ----------
// grid: (F/128, MAXTILES)  -- n-block on x (fast) for A-tile sharing / LLC locality
// MODE 0: v = Xe @ W1^T, hbuf = silu(v)
// MODE 1: v = Xe @ W3^T, hbuf = hbuf * v (in place)
template<int MODE>
__global__ __launch_bounds__(256, 4) void k_gemm1x(
    const u16* __restrict__ xb, const u16* __restrict__ wt,
    u16* __restrict__ hbuf, const int* __restrict__ pair_token,
    const int* __restrict__ ctrl)
{
    int ntiles = ctrl[32];
    int tile = blockIdx.y;
    if (tile >= ntiles) return;
    int e  = ctrl[64 + tile];
    int m0 = ctrl[256 + tile];
    int n0 = blockIdx.x * 128;

    const u16* we = wt + (size_t)e * F_DIM * D_DIM;

    __shared__ __align__(16) u16 As[128 * 32];
    __shared__ __align__(16) u16 Bs[128 * 32];

    int tid  = threadIdx.x;
    int lane = tid & 63, wave = tid >> 6;

    int r_a = tid >> 2, kc = tid & 3;
    int tok0 = pair_token[m0 + r_a];
    int tok1 = pair_token[m0 + r_a + 64];
    const u16* gA0 = xb + (size_t)tok0 * D_DIM + kc * 8;
    const u16* gA1 = xb + (size_t)tok1 * D_DIM + kc * 8;
    const u16* gB0 = we + (size_t)(n0 + r_a) * D_DIM + kc * 8;
    const u16* gB1 = we + (size_t)(n0 + r_a + 64) * D_DIM + kc * 8;
    u16* lA0 = As + tid * 8;
    u16* lA1 = As + tid * 8 + 2048;
    u16* lB0 = Bs + tid * 8;
    u16* lB1 = Bs + tid * 8 + 2048;

    int wr = wave >> 1, wc = wave & 1;
    int quad = lane >> 4, mn = lane & 15;

    f32x4 acc[4][4] = {};

    for (int k0 = 0; k0 < D_DIM; k0 += 32) {
        gl_lds16(gA0 + k0, lA0);
        gl_lds16(gA1 + k0, lA1);
        gl_lds16(gB0 + k0, lB0);
        gl_lds16(gB1 + k0, lB1);
        __syncthreads();

        bf16x8 af[4], bf[4];
#pragma unroll
        for (int i = 0; i < 4; i++)
            af[i] = *(const bf16x8*)(As + (wr * 64 + i * 16 + mn) * 32 + quad * 8);
#pragma unroll
        for (int j = 0; j < 4; j++)
            bf[j] = *(const bf16x8*)(Bs + (wc * 64 + j * 16 + mn) * 32 + quad * 8);
#pragma unroll
        for (int i = 0; i < 4; i++)
#pragma unroll
            for (int j = 0; j < 4; j++)
                acc[i][j] = __builtin_amdgcn_mfma_f32_16x16x32_bf16(af[i], bf[j], acc[i][j], 0, 0, 0);
        __syncthreads();
    }

#pragma unroll
    for (int i = 0; i < 4; i++)
#pragma unroll
        for (int j = 0; j < 4; j++)
#pragma unroll
            for (int r = 0; r < 4; r++) {
                int row = wr * 64 + i * 16 + quad * 4 + r;
                int col = n0 + wc * 64 + j * 16 + mn;
                size_t idx = (size_t)(m0 + row) * F_DIM + col;
                float v = acc[i][j][r];
                if (MODE == 0) {
                    float s = v * (1.f / (1.f + __expf(-v)));   // silu(v1)
                    hbuf[idx] = f2bf(s);
                } else {
                    float s = bf2f(hbuf[idx]);                  // silu(v1)
                    hbuf[idx] = f2bf(s * v);                    // * v3
                }
            }
}

// ---------- kernel 7: GEMM2  out += (h @ W2^T) * w ----------
// grid: (D/128, MAXTILES)
__global__ __launch_bounds__(256, 4) void k_gemm2(
    const u16* __restrict__ h, const u16* __restrict__ w2t,
    float* __restrict__ out, const int* __restrict__ pair_token,
    const float* __restrict__ pair_w, const int* __restrict__ ctrl)
{
    int ntiles = ctrl[32];
    int tile = blockIdx.y;
    if (tile >= ntiles) return;
    int e  = ctrl[64 + tile];
    int m0 = ctrl[256 + tile];
    int n0 = blockIdx.x * 128;

    const u16* w2e = w2t + (size_t)e * D_DIM * F_DIM;

    __shared__ __align__(16) u16 As[128 * 32];
    __shared__ __align__(16) u16 Bs[128 * 32];

    int tid  = threadIdx.x;
    int lane = tid & 63, wave = tid >> 6;

    int r_a = tid >> 2, kc = tid & 3;
    const u16* gA0 = h   + (size_t)(m0 + r_a) * F_DIM + kc * 8;
    const u16* gA1 = h   + (size_t)(m0 + r_a + 64) * F_DIM + kc * 8;
    const u16* gB0 = w2e + (size_t)(n0 + r_a) * F_DIM + kc * 8;
    const u16* gB1 = w2e + (size_t)(n0 + r_a + 64) * F_DIM + kc * 8;
    u16* lA0 = As + tid * 8;
    u16* lA1 = As + tid * 8 + 2048;
    u16* lB0 = Bs + tid * 8;
    u16* lB1 = Bs + tid * 8 + 2048;

    int wr = wave >> 1, wc = wave & 1;
    int quad = lane >> 4, mn = lane & 15;

    f32x4 acc[4][4] = {};

    for (int k0 = 0; k0 < F_DIM; k0 += 32) {
        gl_lds16(gA0 + k0, lA0);
        gl_lds16(gA1 + k0, lA1);
        gl_lds16(gB0 + k0, lB0);
        gl_lds16(gB1 + k0, lB1);
        __syncthreads();

        bf16x8 af[4], bf[4];
#pragma unroll
        for (int i = 0; i < 4; i++)
            af[i] = *(const bf16x8*)(As + (wr * 64 + i * 16 + mn) * 32 + quad * 8);
#pragma unroll
        for (int j = 0; j < 4; j++)
            bf[j] = *(const bf16x8*)(Bs + (wc * 64 + j * 16 + mn) * 32 + quad * 8);
#pragma unroll
        for (int i = 0; i < 4; i++)
#pragma unroll
            for (int j = 0; j < 4; j++)
                acc[i][j] = __builtin_amdgcn_mfma_f32_16x16x32_bf16(af[i], bf[j], acc[i][j], 0, 0, 0);
        __syncthreads();
    }

#pragma unroll
    for (int i = 0; i < 4; i++)
#pragma unroll
        for (int r = 0; r < 4; r++) {
            int row = wr * 64 + i * 16 + quad * 4 + r;
            int prow = m0 + row;
            int tokv = pair_token[prow];
            float wv = pair_w[prow];
#pragma unroll
            for (int j = 0; j < 4; j++) {
                int col = n0 + wc * 64 + j * 16 + mn;
                atomicAdd(&out[(size_t)tokv * D_DIM + col], acc[i][j][r] * wv);
            }
        }
}

// ---------- launch ----------
extern "C" void kernel_launch(void* const* d_in, const int* in_sizes, int n_in,
                              void* d_out, int out_size, void* d_ws, size_t ws_size,
                              hipStream_t stream)
{
    const float* x      = (const float*)d_in[0];
    const float* gate_w = (const float*)d_in[1];
    const float* W1     = (const float*)d_in[2];
    const float* W3     = (const float*)d_in[3];
    const float* W2     = (const float*)d_in[4];
    float* out = (float*)d_out;
    float* logits_out = out + (size_t)T_TOKENS * D_DIM;

    char* ws = (char*)d_ws;
    int*   ctrl       = (int*)ws;                    // 4096 B (incl tile map)
    int*   pair_token = (int*)(ws + 4096);           // 69632 B
    float* pair_w     = (float*)(ws + 4096 + 69632); // 69632 B
    int*   ti         = (int*)(ws + 143360);         // 65536 B
    float* tw         = (float*)(ws + 208896);       // 65536 B
    u16*   xb         = (u16*)(ws + 1048576);        // 16 MiB
    u16*   w1t        = (u16*)(ws + 17825792);       // 64 MiB
    u16*   w3t        = (u16*)(ws + 84934656);       // 64 MiB
    u16*   w2t        = (u16*)(ws + 152043520);      // 64 MiB
    u16*   h          = (u16*)(ws + 219152384);      // 136 MiB

    hipMemsetAsync(d_out, 0, (size_t)T_TOKENS * D_DIM * sizeof(float), stream);
    hipMemsetAsync(ws, 0, 143360, stream);

    k_router<<<T_TOKENS / 4, 256, 0, stream>>>(x, gate_w, logits_out, ti, tw, ctrl);
    k_plan<<<1, 64, 0, stream>>>(ctrl);
    k_scatter<<<T_TOKENS / 256, 256, 0, stream>>>(ti, tw, ctrl, pair_token, pair_w);

    k_cvt_x<<<(T_TOKENS * D_DIM) / (256 * 4), 256, 0, stream>>>(x, xb);
    dim3 tg1(128, 32, NE);  // W1/W3: R=1024, C=4096
    k_transpose_cvt<<<tg1, 256, 0, stream>>>(W1, w1t, D_DIM, F_DIM);
    k_transpose_cvt<<<tg1, 256, 0, stream>>>(W3, w3t, D_DIM, F_DIM);
    dim3 tg2(32, 128, NE);  // W2: R=4096, C=1024
    k_transpose_cvt<<<tg2, 256, 0, stream>>>(W2, w2t, F_DIM, D_DIM);

    dim3 g1(F_DIM / 128, MAXTILES);   // n-block fast, tile slow
    k_gemm1x<0><<<g1, 256, 0, stream>>>(xb, w1t, h, pair_token, ctrl);
    k_gemm1x<1><<<g1, 256, 0, stream>>>(xb, w3t, h, pair_token, ctrl);
    dim3 g2(D_DIM / 128, MAXTILES);
    k_gemm2<<<g2, 256, 0, stream>>>(h, w2t, out, pair_token, pair_w, ctrl);
}